// Round 8
// baseline (136.043 us; speedup 1.0000x reference)
//
#include <hip/hip_runtime.h>
#include <hip/hip_bf16.h>
#include <math.h>

#define E_DIM 128
#define S_LEN 2048
#define B_N   8
#define BS    (B_N * S_LEN)       // 16384 positions
#define CHUNK 64
#define NCHUNK (S_LEN / CHUNK)    // 32

typedef unsigned short u16;
typedef _Float16 f16;
typedef _Float16 f16x2 __attribute__((ext_vector_type(2)));
typedef _Float16 f16x8 __attribute__((ext_vector_type(8)));
typedef float    f32x16 __attribute__((ext_vector_type(16)));

// ---------------------------------------------------------------------------
// Kernel 1 (fused): blocks 0..1023 = W pre-convert; blocks 1024..1279 = dense.
// wconv: fp32 [c][a][p] -> f16 W2 layout where each wave-private B-fragment
// load in k_main is a DENSE 1KB-per-instruction read:
//   quad t (8 u16): l31=t&31, hi=(t>>5)&1, ks=(t>>6)&7, cch=(t>>9)&3, a=t>>11
//   holds src quad (c = cch*32+l31, a, qs = ks*2+hi)   [p = qs*8 .. +8)
// k_main lane l=hi*32+l31 then reads W[c=cch*32+l31][p=ks*16+hi*8..+8] at
// linear offset ((a*4+cch)*8+ks)*512 + l*8  -> contiguous across the wave.
// ---------------------------------------------------------------------------
__global__ __launch_bounds__(256) void k_pre(const float* __restrict__ x,
                                             const float* __restrict__ dw,
                                             const float* __restrict__ db,
                                             const float* __restrict__ cm,
                                             float* __restrict__ hout,
                                             u16* __restrict__ wb) {
    if (blockIdx.x < 1024) {
        int t = blockIdx.x * 256 + threadIdx.x;     // one 8-elem quad each
        int l31 = t & 31, hi = (t >> 5) & 1, ks = (t >> 6) & 7;
        int cch = (t >> 9) & 3, a = t >> 11;
        int c = cch * 32 + l31, qs = ks * 2 + hi;
        const float* src = cm + (((long)(c << 7) + a) << 7) + (qs << 3);
        float4 v0 = ((const float4*)src)[0];
        float4 v1 = ((const float4*)src)[1];
        union { f16 f[8]; uint4 v; } o;
        o.f[0] = (f16)v0.x; o.f[1] = (f16)v0.y; o.f[2] = (f16)v0.z; o.f[3] = (f16)v0.w;
        o.f[4] = (f16)v1.x; o.f[5] = (f16)v1.y; o.f[6] = (f16)v1.z; o.f[7] = (f16)v1.w;
        ((uint4*)wb)[t] = o.v;
        return;
    }
    __shared__ float Wl[E_DIM * E_DIM];   // [k][c], 64KB
    const int t = threadIdx.x;
    const long r0 = (long)(blockIdx.x - 1024) * 64;

    float4* Wl4 = (float4*)Wl;
    const float4* w4 = (const float4*)dw;
#pragma unroll
    for (int i = 0; i < 16; ++i) Wl4[t + 256 * i] = w4[t + 256 * i];
    __syncthreads();

    const int cq = t & 31;
    const int rg = t >> 5;
    float4 bb = ((const float4*)db)[cq];
    float acc[8][4];
#pragma unroll
    for (int i = 0; i < 8; ++i) {
        acc[i][0] = bb.x; acc[i][1] = bb.y; acc[i][2] = bb.z; acc[i][3] = bb.w;
    }
#pragma unroll 4
    for (int k = 0; k < E_DIM; ++k) {
        float4 wv = Wl4[k * 32 + cq];
#pragma unroll
        for (int i = 0; i < 8; ++i) {
            float xv = x[(r0 + rg * 8 + i) * E_DIM + k];
            acc[i][0] += xv * wv.x;
            acc[i][1] += xv * wv.y;
            acc[i][2] += xv * wv.z;
            acc[i][3] += xv * wv.w;
        }
    }
    float4* h4 = (float4*)(hout + r0 * E_DIM);
#pragma unroll
    for (int i = 0; i < 8; ++i) {
        float4 o;
        o.x = acc[i][0]; o.y = acc[i][1]; o.z = acc[i][2]; o.w = acc[i][3];
        h4[(rg * 8 + i) * 32 + cq] = o;
    }
}

// ---------------------------------------------------------------------------
// Kernel 2: chunked decayed scan. Writes f16 LOCAL prefix into sb16 (carry
// applied inside k_main), f16 transposed h into hT[a][pos], fp32 chunk
// carry-out f_j into fc.
// ---------------------------------------------------------------------------
__global__ __launch_bounds__(128) void k_scan(const float* __restrict__ h,
                                              u16* __restrict__ sb16,
                                              float* __restrict__ fc,
                                              u16* __restrict__ hT) {
    const int b = blockIdx.x >> 5;
    const int j = blockIdx.x & 31;
    const int e = threadIdx.x;
    const float inv_d = (float)(1.0 / 1.2);
    const int pos0 = b * S_LEN + j * CHUNK;
    long base = (long)pos0 * E_DIM + e;
    float carry = 0.f;
    union { u16 u[8]; uint4 v; } hb;
#pragma unroll 1
    for (int i0 = 0; i0 < CHUNK; i0 += 8) {
#pragma unroll
        for (int k = 0; k < 8; ++k) {
            float hv = h[base + (long)(i0 + k) * E_DIM];
            union { f16 f; u16 u; } cu; cu.f = (f16)carry;
            sb16[base + (long)(i0 + k) * E_DIM] = cu.u;
            union { f16 f; u16 u; } hu; hu.f = (f16)hv;
            hb.u[k] = hu.u;
            carry = (carry + hv) * inv_d;
        }
        *(uint4*)&hT[(size_t)e * BS + pos0 + i0] = hb.v;
    }
    fc[(b * NCHUNK + j) * E_DIM + e] = carry;
}

// ---------------------------------------------------------------------------
// Kernel 3 (main): f16 MFMA einsum, WAVE-PRIVATE pipelines, ZERO barriers in
// the K-loop.  Grid 4096 x 64 thr (1 wave/block).  Job = (mb, cch, r, kq):
// 128 rows x 32 c x 32 a-slices x half-p.  B-frags load global->VGPR direct
// from the W2 layout (4 x dense 1KB dwordx4 per slice), register
// double-buffered one slice ahead (covers L2 latency; no vmcnt(0) stalls,
// no cross-wave sync).  ~190 VGPR -> ~10 independent waves/CU.
// s in 64 VGPRs; h in 8KB LDS (lgkm path); carry/decay fused in prologue.
// Bijective XCD swizzle: 4 (cch,r,kq) combos per XCD -> W2 512KB L2-resident.
// Partials (4 r x 2 kq = 8 per output) via hw fp32 atomics into zeroed out.
// ---------------------------------------------------------------------------
__global__ __launch_bounds__(64, 2) void k_main(const u16* __restrict__ hT,
                                                const u16* __restrict__ sb16,
                                                const float* __restrict__ fc,
                                                const u16* __restrict__ w2,
                                                float* __restrict__ out,
                                                float dm64) {
    __shared__ u16 h16[32 * 128];     // [a_local][row_local], 8 KB
    __shared__ float carr[2][E_DIM];  // carry-in for the 2 chunks, 1 KB
    const int l = threadIdx.x;        // 0..63
    const int l31 = l & 31, hi = l >> 5;

    // bijective XCD swizzle: xcd = bid&7 serves 4 (cch,r,kq) combos
    const int bid = blockIdx.x;
    const int x = bid & 7, i = bid >> 3;
    const int combo = x * 4 + (i >> 7);     // 0..31
    const int mb  = i & 127;
    const int cch = combo & 3;              // c-chunk (32 cols)
    const int r   = (combo >> 2) & 3;       // K-quarter (32 a-slices)
    const int kq  = combo >> 4;             // p-half (64 p)
    const int row_base = mb * 128;

    // ---- stage h16 via global_load_lds (linear dst, per-lane src) ----
#pragma unroll
    for (int it = 0; it < 8; ++it) {
        int idx = it * 64 + l;              // 16B quad index
        int al = idx >> 4, part = idx & 15;
        const u16* src = hT + (size_t)(r * 32 + al) * BS + row_base + part * 8;
        __builtin_amdgcn_global_load_lds(
            (const __attribute__((address_space(1))) void*)src,
            (__attribute__((address_space(3))) void*)&h16[idx * 8], 16, 0, 0);
    }

    // ---- fused carry: weighted-sum form (parallel loads, no serial chain)
    const int bb = row_base >> 11;
    const int j0 = (row_base >> 6) & 31;    // first chunk (j0+1 = second)
    const float L2D = 0.26303440583379383f; // log2(1.2)
    {
        const float d2 = dm64 * dm64, d3 = d2 * dm64, d4 = d3 * dm64;
#pragma unroll
        for (int es = 0; es < 2; ++es) {
            int e = l + es * 64;
            const float* fp = fc + (size_t)(bb * NCHUNK) * E_DIM + e;
            float c0 = 0.f;
            int jj = 0;
            for (; jj + 4 <= j0; jj += 4) {
                float f0 = fp[(jj + 0) * E_DIM], f1 = fp[(jj + 1) * E_DIM];
                float f2 = fp[(jj + 2) * E_DIM], f3 = fp[(jj + 3) * E_DIM];
                c0 = c0 * d4 + f0 * d3 + f1 * d2 + f2 * dm64 + f3;
            }
            for (; jj < j0; ++jj) c0 = c0 * dm64 + fp[jj * E_DIM];
            carr[0][e] = c0;
            carr[1][e] = fp[j0 * E_DIM] + c0 * dm64;   // carry into chunk j0+1
        }
    }
    __syncthreads();   // 1-wave barrier: drains h16 DMA + carr writes

    // ---- s fragments: s2[rb][ksl*4+q] = f16(local_prefix + carr*1.2^-i)
    f16x2 s2[4][16];
#pragma unroll
    for (int rb = 0; rb < 4; ++rb) {
        const int row = row_base + rb * 32 + l31;
        const float f = exp2f(-L2D * (float)(row & 63));
        const int ch = rb >> 1;
#pragma unroll
        for (int ksl = 0; ksl < 4; ++ksl) {
            const int pbase = kq * 64 + ksl * 16 + hi * 8;
            union { uint4 u; u16 us[8]; } uu;
            uu.u = *(const uint4*)(sb16 + (size_t)row * E_DIM + pbase);
#pragma unroll
            for (int q = 0; q < 4; ++q) {
                union { f16 f; u16 u; } a0; a0.u = uu.us[2 * q];
                union { f16 f; u16 u; } a1; a1.u = uu.us[2 * q + 1];
                f16x2 pr;
                pr.x = (f16)((float)a0.f + carr[ch][pbase + 2 * q] * f);
                pr.y = (f16)((float)a1.f + carr[ch][pbase + 2 * q + 1] * f);
                s2[rb][ksl * 4 + q] = pr;
            }
        }
    }

    f32x16 acc[4];
#pragma unroll
    for (int rb = 0; rb < 4; ++rb)
#pragma unroll
        for (int g = 0; g < 16; ++g) acc[rb][g] = 0.f;

    // per-lane W2 base: slice sl at +sl*16384, ksl at +ksl*512 (u16 units)
    const u16* wbase = w2 + (size_t)(r * 32) * 16384 + cch * 4096 + kq * 2048 + l * 8;

#define LOADB(dst, sl) {                                                      \
    const u16* _p = wbase + (size_t)(sl) * 16384;                             \
    _Pragma("unroll")                                                         \
    for (int _k = 0; _k < 4; ++_k) dst[_k] = *(const f16x8*)(_p + _k * 512); }

#define LOADH(dst, sl) {                                                      \
    _Pragma("unroll")                                                         \
    for (int _rb = 0; _rb < 4; ++_rb) dst[_rb] = h16[(sl) * 128 + _rb * 32 + l31]; }

#define COMPUTE(bf, hv)                                                       \
    _Pragma("unroll")                                                         \
    for (int _ksl = 0; _ksl < 4; ++_ksl) {                                    \
        _Pragma("unroll")                                                     \
        for (int _rb = 0; _rb < 4; ++_rb) {                                   \
            union { u16 u[2]; f16x2 v; } _hh;                                 \
            _hh.u[0] = hv[_rb]; _hh.u[1] = hv[_rb];                           \
            union { f16x2 h2[4]; f16x8 v; } _A;                               \
            _Pragma("unroll")                                                 \
            for (int _q = 0; _q < 4; ++_q)                                    \
                _A.h2[_q] = _hh.v * s2[_rb][_ksl * 4 + _q];                   \
            acc[_rb] = __builtin_amdgcn_mfma_f32_32x32x16_f16(                \
                _A.v, bf[_ksl], acc[_rb], 0, 0, 0);                           \
        }                                                                     \
    }

    f16x8 bA[4], bB[4];
    u16 hA[4], hB[4];
    LOADB(bA, 0); LOADH(hA, 0);

#pragma unroll 1
    for (int s2i = 0; s2i < 16; ++s2i) {
        const int sl = s2i * 2;
        LOADB(bB, sl + 1); LOADH(hB, sl + 1);
        COMPUTE(bA, hA);
        if (s2i < 15) { LOADB(bA, sl + 2); LOADH(hA, sl + 2); }
        COMPUTE(bB, hB);
    }
#undef LOADB
#undef LOADH
#undef COMPUTE

    // epilogue: partials (4 r x 2 kq) via hw fp32 atomics (out pre-zeroed)
    const int col = cch * 32 + l31;
#pragma unroll
    for (int rb = 0; rb < 4; ++rb)
#pragma unroll
        for (int g = 0; g < 16; ++g) {
            int rowl = (g & 3) + 8 * (g >> 2) + 4 * hi;   // m101 C/D map
            long row = (long)row_base + rb * 32 + rowl;
            unsafeAtomicAdd(&out[row * E_DIM + col], acc[rb][g]);
        }
}

// ---------------------------------------------------------------------------
// Kernel 4: residual + LayerNorm, in place on d_out. 8 rows/block.
// ---------------------------------------------------------------------------
__global__ __launch_bounds__(256) void k_ln(float* __restrict__ out,
                                            const float* __restrict__ h,
                                            const float* __restrict__ gamma,
                                            const float* __restrict__ beta) {
    const int t = threadIdx.x;
    const int l32 = t & 31, rl = t >> 5;
    const long row = (long)blockIdx.x * 8 + rl;
    float4 v  = ((const float4*)out)[row * 32 + l32];
    float4 hv = ((const float4*)h)[row * 32 + l32];
    v.x += hv.x; v.y += hv.y; v.z += hv.z; v.w += hv.w;
    float ls = v.x + v.y + v.z + v.w;
    float lq = v.x * v.x + v.y * v.y + v.z * v.z + v.w * v.w;
#pragma unroll
    for (int m = 1; m < 32; m <<= 1) {
        ls += __shfl_xor(ls, m, 64);
        lq += __shfl_xor(lq, m, 64);
    }
    float mean = ls * (1.f / 128.f);
    float var  = lq * (1.f / 128.f) - mean * mean;
    float inv  = rsqrtf(var + 1e-3f);
    float4 g = ((const float4*)gamma)[l32];
    float4 b = ((const float4*)beta)[l32];
    float4 o;
    o.x = (v.x - mean) * inv * g.x + b.x;
    o.y = (v.y - mean) * inv * g.y + b.y;
    o.z = (v.z - mean) * inv * g.z + b.z;
    o.w = (v.w - mean) * inv * g.w + b.w;
    ((float4*)out)[row * 32 + l32] = o;
}

// ---------------------------------------------------------------------------
extern "C" void kernel_launch(void* const* d_in, const int* in_sizes, int n_in,
                              void* d_out, int out_size, void* d_ws, size_t ws_size,
                              hipStream_t stream) {
    const float* x     = (const float*)d_in[0];
    const float* dw    = (const float*)d_in[1];
    const float* db    = (const float*)d_in[2];
    const float* cm    = (const float*)d_in[3];
    const float* gamma = (const float*)d_in[4];
    const float* beta  = (const float*)d_in[5];
    float* outp = (float*)d_out;

    float* ws = (float*)d_ws;
    float* h    = ws;                                     // BS*E f32 (8 MB)
    float* fc   = ws + (size_t)BS * E_DIM;                // 32768 f32 (raw f_j)
    u16*   wb   = (u16*)(fc + B_N * NCHUNK * E_DIM);      // E^3 f16 (4 MB)
    u16*   hT   = wb + (size_t)2097152;                   // [a][pos] f16 (4 MB)
    u16*   sb16 = hT + (size_t)BS * E_DIM;                // [pos][p] f16 (4 MB)

    float dm64 = (float)pow(1.2, -64.0);   // host-side, pure CPU

    hipMemsetAsync(d_out, 0, (size_t)BS * E_DIM * sizeof(float), stream);
    k_pre <<<dim3(1280), dim3(256), 0, stream>>>(x, dw, db, cm, h, wb);
    k_scan<<<dim3(B_N * NCHUNK), dim3(128), 0, stream>>>(h, sb16, fc, hT);
    k_main<<<dim3(4096), dim3(64), 0, stream>>>(hT, sb16, fc, wb, outp, dm64);
    k_ln  <<<dim3(BS / 8), dim3(256), 0, stream>>>(outp, h, gamma, beta);
}

// Round 9
// 130.648 us; speedup vs baseline: 1.0413x; 1.0413x over previous
//
#include <hip/hip_runtime.h>
#include <hip/hip_bf16.h>
#include <math.h>

#define E_DIM 128
#define S_LEN 2048
#define B_N   8
#define BS    (B_N * S_LEN)       // 16384 positions
#define CHUNK 64
#define NCHUNK (S_LEN / CHUNK)    // 32

typedef unsigned short u16;
typedef _Float16 f16;
typedef _Float16 f16x2 __attribute__((ext_vector_type(2)));
typedef _Float16 f16x8 __attribute__((ext_vector_type(8)));
typedef float    f32x16 __attribute__((ext_vector_type(16)));

// ---------------------------------------------------------------------------
// Kernel 1 (fused): blocks 0..1023 = W pre-convert; blocks 1024..1279 = dense.
// wconv: fp32 [c][a][p] -> f16 W2 layout where each wave-private B-fragment
// load in k_main is a DENSE 1KB-per-instruction read:
//   quad t (8 u16): l31=t&31, hi=(t>>5)&1, ks=(t>>6)&7, cch=(t>>9)&3, a=t>>11
//   holds src quad (c = cch*32+l31, a, qs = ks*2+hi)   [p = qs*8 .. +8)
// k_main lane l=hi*32+l31 reads W[c=cch*32+l31][p=ks*16+hi*8..+8] at linear
// offset ((a*4+cch)*8+ks)*512 + l*8 -> contiguous across the wave.
// ---------------------------------------------------------------------------
__global__ __launch_bounds__(256) void k_pre(const float* __restrict__ x,
                                             const float* __restrict__ dw,
                                             const float* __restrict__ db,
                                             const float* __restrict__ cm,
                                             float* __restrict__ hout,
                                             u16* __restrict__ wb) {
    if (blockIdx.x < 1024) {
        int t = blockIdx.x * 256 + threadIdx.x;     // one 8-elem quad each
        int l31 = t & 31, hi = (t >> 5) & 1, ks = (t >> 6) & 7;
        int cch = (t >> 9) & 3, a = t >> 11;
        int c = cch * 32 + l31, qs = ks * 2 + hi;
        const float* src = cm + (((long)(c << 7) + a) << 7) + (qs << 3);
        float4 v0 = ((const float4*)src)[0];
        float4 v1 = ((const float4*)src)[1];
        union { f16 f[8]; uint4 v; } o;
        o.f[0] = (f16)v0.x; o.f[1] = (f16)v0.y; o.f[2] = (f16)v0.z; o.f[3] = (f16)v0.w;
        o.f[4] = (f16)v1.x; o.f[5] = (f16)v1.y; o.f[6] = (f16)v1.z; o.f[7] = (f16)v1.w;
        ((uint4*)wb)[t] = o.v;
        return;
    }
    __shared__ float Wl[E_DIM * E_DIM];   // [k][c], 64KB
    const int t = threadIdx.x;
    const long r0 = (long)(blockIdx.x - 1024) * 64;

    float4* Wl4 = (float4*)Wl;
    const float4* w4 = (const float4*)dw;
#pragma unroll
    for (int i = 0; i < 16; ++i) Wl4[t + 256 * i] = w4[t + 256 * i];
    __syncthreads();

    const int cq = t & 31;
    const int rg = t >> 5;
    float4 bb = ((const float4*)db)[cq];
    float acc[8][4];
#pragma unroll
    for (int i = 0; i < 8; ++i) {
        acc[i][0] = bb.x; acc[i][1] = bb.y; acc[i][2] = bb.z; acc[i][3] = bb.w;
    }
#pragma unroll 4
    for (int k = 0; k < E_DIM; ++k) {
        float4 wv = Wl4[k * 32 + cq];
#pragma unroll
        for (int i = 0; i < 8; ++i) {
            float xv = x[(r0 + rg * 8 + i) * E_DIM + k];
            acc[i][0] += xv * wv.x;
            acc[i][1] += xv * wv.y;
            acc[i][2] += xv * wv.z;
            acc[i][3] += xv * wv.w;
        }
    }
    float4* h4 = (float4*)(hout + r0 * E_DIM);
#pragma unroll
    for (int i = 0; i < 8; ++i) {
        float4 o;
        o.x = acc[i][0]; o.y = acc[i][1]; o.z = acc[i][2]; o.w = acc[i][3];
        h4[(rg * 8 + i) * 32 + cq] = o;
    }
}

// ---------------------------------------------------------------------------
// Kernel 2: chunked decayed scan. Writes f16 LOCAL prefix into sb16 (carry
// applied inside k_main), f16 transposed h into hT[a][pos], fp32 chunk
// carry-out f_j into fc.
// ---------------------------------------------------------------------------
__global__ __launch_bounds__(128) void k_scan(const float* __restrict__ h,
                                              u16* __restrict__ sb16,
                                              float* __restrict__ fc,
                                              u16* __restrict__ hT) {
    const int b = blockIdx.x >> 5;
    const int j = blockIdx.x & 31;
    const int e = threadIdx.x;
    const float inv_d = (float)(1.0 / 1.2);
    const int pos0 = b * S_LEN + j * CHUNK;
    long base = (long)pos0 * E_DIM + e;
    float carry = 0.f;
    union { u16 u[8]; uint4 v; } hb;
#pragma unroll 1
    for (int i0 = 0; i0 < CHUNK; i0 += 8) {
#pragma unroll
        for (int k = 0; k < 8; ++k) {
            float hv = h[base + (long)(i0 + k) * E_DIM];
            union { f16 f; u16 u; } cu; cu.f = (f16)carry;
            sb16[base + (long)(i0 + k) * E_DIM] = cu.u;
            union { f16 f; u16 u; } hu; hu.f = (f16)hv;
            hb.u[k] = hu.u;
            carry = (carry + hv) * inv_d;
        }
        *(uint4*)&hT[(size_t)e * BS + pos0 + i0] = hb.v;
    }
    fc[(b * NCHUNK + j) * E_DIM + e] = carry;
}

// ---------------------------------------------------------------------------
// Kernel 3 (main): f16 MFMA einsum; 4 INDEPENDENT wave-jobs per 256-thr
// block, zero K-loop barriers.  Grid 1024: block = (combo = bid&7 -> r,kq;
// mb = bid>>3); wave w = c-chunk cch.  Wave-job: 128 rows x 32 c x
// 32 a-slices x 64 p (kq half).  B-frags global->VGPR from W2 (4 x dense
// 1KB dwordx4 per slice), 4-buffer depth-2 register prefetch (static names,
// rule 20).  Each B-frag reused across 4 rb (row-groups) -> B traffic
// 256B/MFMA from L2 (XCD-pinned 512KB working set).  s in 64 VGPRs; h in
// 8KB LDS shared by the 4 waves; carry/decay fused in shared prologue.
// Partials (4 r x 2 kq) via hw fp32 atomics into zeroed out.
// ---------------------------------------------------------------------------
__global__ __launch_bounds__(256, 2) void k_main(const u16* __restrict__ hT,
                                                 const u16* __restrict__ sb16,
                                                 const float* __restrict__ fc,
                                                 const u16* __restrict__ w2,
                                                 float* __restrict__ out,
                                                 float dm64) {
    __shared__ u16 h16[32 * 128];     // [a_local][row_local], 8 KB
    __shared__ float carr[2][E_DIM];  // carry-in for the 2 chunks, 1 KB
    const int t = threadIdx.x;
    const int w = t >> 6, l = t & 63;
    const int l31 = l & 31, hi = l >> 5;

    const int bid = blockIdx.x;
    const int combo = bid & 7;            // XCD-pinned
    const int r   = combo & 3;            // K-quarter (32 a-slices)
    const int kq  = combo >> 2;           // p-half (64 p)
    const int mb  = bid >> 3;             // 0..127
    const int cch = w;                    // wave-private c-chunk (32 cols)
    const int row_base = mb * 128;

    // ---- shared prologue: stage h16 (cooperative, 2 quads/thread) ----
#pragma unroll
    for (int it = 0; it < 2; ++it) {
        int idx = it * 256 + t;           // 16B quad index, 0..511
        int al = idx >> 4, part = idx & 15;
        const u16* src = hT + (size_t)(r * 32 + al) * BS + row_base + part * 8;
        __builtin_amdgcn_global_load_lds(
            (const __attribute__((address_space(1))) void*)src,
            (__attribute__((address_space(3))) void*)&h16[idx * 8], 16, 0, 0);
    }

    // ---- shared carry: weighted-sum form, one (ch,e) per thread ----
    const int bb = row_base >> 11;
    const int j0 = (row_base >> 6) & 31;
    const float L2D = 0.26303440583379383f; // log2(1.2)
    {
        const int ch = t >> 7, e = t & 127;
        const float d2 = dm64 * dm64, d3 = d2 * dm64, d4 = d3 * dm64;
        const float* fp = fc + (size_t)(bb * NCHUNK) * E_DIM + e;
        float c0 = 0.f;
        int jj = 0;
        for (; jj + 4 <= j0; jj += 4) {
            float f0 = fp[(jj + 0) * E_DIM], f1 = fp[(jj + 1) * E_DIM];
            float f2 = fp[(jj + 2) * E_DIM], f3 = fp[(jj + 3) * E_DIM];
            c0 = c0 * d4 + f0 * d3 + f1 * d2 + f2 * dm64 + f3;
        }
        for (; jj < j0; ++jj) c0 = c0 * dm64 + fp[jj * E_DIM];
        if (ch == 0) carr[0][e] = c0;
        else         carr[1][e] = fp[j0 * E_DIM] + c0 * dm64;
    }
    __syncthreads();   // h16 DMA + carr visible to all 4 waves

    // ---- s fragments (wave-private, kq half): f16(local + carr*1.2^-i) ----
    f16x2 s2[4][16];
#pragma unroll
    for (int rb = 0; rb < 4; ++rb) {
        const int row = row_base + rb * 32 + l31;
        const float f = exp2f(-L2D * (float)(row & 63));
        const int ch = rb >> 1;
#pragma unroll
        for (int ksl = 0; ksl < 4; ++ksl) {
            const int pbase = kq * 64 + ksl * 16 + hi * 8;
            union { uint4 u; u16 us[8]; } uu;
            uu.u = *(const uint4*)(sb16 + (size_t)row * E_DIM + pbase);
#pragma unroll
            for (int q = 0; q < 4; ++q) {
                union { f16 f; u16 u; } a0; a0.u = uu.us[2 * q];
                union { f16 f; u16 u; } a1; a1.u = uu.us[2 * q + 1];
                f16x2 pr;
                pr.x = (f16)((float)a0.f + carr[ch][pbase + 2 * q] * f);
                pr.y = (f16)((float)a1.f + carr[ch][pbase + 2 * q + 1] * f);
                s2[rb][ksl * 4 + q] = pr;
            }
        }
    }

    f32x16 acc[4];
#pragma unroll
    for (int rb = 0; rb < 4; ++rb)
#pragma unroll
        for (int g = 0; g < 16; ++g) acc[rb][g] = 0.f;

    // per-lane W2 base (u16 units): slice sl at +sl*16384, ksl at +ksl*512
    const u16* wbase = w2 + (size_t)(r * 32) * 16384 + cch * 4096 + kq * 2048 + l * 8;

#define LOADB(dst, sl) {                                                      \
    const u16* _p = wbase + (size_t)(sl) * 16384;                             \
    _Pragma("unroll")                                                         \
    for (int _k = 0; _k < 4; ++_k) dst[_k] = *(const f16x8*)(_p + _k * 512); }

#define LOADH(dst, sl) {                                                      \
    _Pragma("unroll")                                                         \
    for (int _rb = 0; _rb < 4; ++_rb) dst[_rb] = h16[(sl) * 128 + _rb * 32 + l31]; }

#define COMPUTE(bf, hv) {                                                     \
    union { u16 u[2]; f16x2 v; } _hp[4];                                      \
    _Pragma("unroll")                                                         \
    for (int _rb = 0; _rb < 4; ++_rb) {                                       \
        _hp[_rb].u[0] = hv[_rb]; _hp[_rb].u[1] = hv[_rb];                     \
    }                                                                         \
    _Pragma("unroll")                                                         \
    for (int _ksl = 0; _ksl < 4; ++_ksl) {                                    \
        _Pragma("unroll")                                                     \
        for (int _rb = 0; _rb < 4; ++_rb) {                                   \
            union { f16x2 h2[4]; f16x8 v; } _A;                               \
            _Pragma("unroll")                                                 \
            for (int _q = 0; _q < 4; ++_q)                                    \
                _A.h2[_q] = _hp[_rb].v * s2[_rb][_ksl * 4 + _q];              \
            acc[_rb] = __builtin_amdgcn_mfma_f32_32x32x16_f16(                \
                _A.v, bf[_ksl], acc[_rb], 0, 0, 0);                           \
        }                                                                     \
    }}

    f16x8 b0[4], b1[4], b2[4], b3[4];
    u16 h0[4], h1[4], h2[4], h3[4];
    LOADB(b0, 0); LOADH(h0, 0);
    LOADB(b1, 1); LOADH(h1, 1);

#pragma unroll 1
    for (int sq = 0; sq < 8; ++sq) {
        const int sl = sq * 4;
        if (sl + 2 < 32) { LOADB(b2, sl + 2); LOADH(h2, sl + 2); }
        COMPUTE(b0, h0);
        if (sl + 3 < 32) { LOADB(b3, sl + 3); LOADH(h3, sl + 3); }
        COMPUTE(b1, h1);
        if (sl + 4 < 32) { LOADB(b0, sl + 4); LOADH(h0, sl + 4); }
        COMPUTE(b2, h2);
        if (sl + 5 < 32) { LOADB(b1, sl + 5); LOADH(h1, sl + 5); }
        COMPUTE(b3, h3);
    }
#undef LOADB
#undef LOADH
#undef COMPUTE

    // epilogue: partials (4 r x 2 kq) via hw fp32 atomics (out pre-zeroed)
    const int col = cch * 32 + l31;
#pragma unroll
    for (int rb = 0; rb < 4; ++rb)
#pragma unroll
        for (int g = 0; g < 16; ++g) {
            int rowl = (g & 3) + 8 * (g >> 2) + 4 * hi;   // m101 C/D map
            long row = (long)row_base + rb * 32 + rowl;
            unsafeAtomicAdd(&out[row * E_DIM + col], acc[rb][g]);
        }
}

// ---------------------------------------------------------------------------
// Kernel 4: residual + LayerNorm, in place on d_out. 8 rows/block.
// ---------------------------------------------------------------------------
__global__ __launch_bounds__(256) void k_ln(float* __restrict__ out,
                                            const float* __restrict__ h,
                                            const float* __restrict__ gamma,
                                            const float* __restrict__ beta) {
    const int t = threadIdx.x;
    const int l32 = t & 31, rl = t >> 5;
    const long row = (long)blockIdx.x * 8 + rl;
    float4 v  = ((const float4*)out)[row * 32 + l32];
    float4 hv = ((const float4*)h)[row * 32 + l32];
    v.x += hv.x; v.y += hv.y; v.z += hv.z; v.w += hv.w;
    float ls = v.x + v.y + v.z + v.w;
    float lq = v.x * v.x + v.y * v.y + v.z * v.z + v.w * v.w;
#pragma unroll
    for (int m = 1; m < 32; m <<= 1) {
        ls += __shfl_xor(ls, m, 64);
        lq += __shfl_xor(lq, m, 64);
    }
    float mean = ls * (1.f / 128.f);
    float var  = lq * (1.f / 128.f) - mean * mean;
    float inv  = rsqrtf(var + 1e-3f);
    float4 g = ((const float4*)gamma)[l32];
    float4 b = ((const float4*)beta)[l32];
    float4 o;
    o.x = (v.x - mean) * inv * g.x + b.x;
    o.y = (v.y - mean) * inv * g.y + b.y;
    o.z = (v.z - mean) * inv * g.z + b.z;
    o.w = (v.w - mean) * inv * g.w + b.w;
    ((float4*)out)[row * 32 + l32] = o;
}

// ---------------------------------------------------------------------------
extern "C" void kernel_launch(void* const* d_in, const int* in_sizes, int n_in,
                              void* d_out, int out_size, void* d_ws, size_t ws_size,
                              hipStream_t stream) {
    const float* x     = (const float*)d_in[0];
    const float* dw    = (const float*)d_in[1];
    const float* db    = (const float*)d_in[2];
    const float* cm    = (const float*)d_in[3];
    const float* gamma = (const float*)d_in[4];
    const float* beta  = (const float*)d_in[5];
    float* outp = (float*)d_out;

    float* ws = (float*)d_ws;
    float* h    = ws;                                     // BS*E f32 (8 MB)
    float* fc   = ws + (size_t)BS * E_DIM;                // 32768 f32 (raw f_j)
    u16*   wb   = (u16*)(fc + B_N * NCHUNK * E_DIM);      // E^3 f16 (4 MB)
    u16*   hT   = wb + (size_t)2097152;                   // [a][pos] f16 (4 MB)
    u16*   sb16 = hT + (size_t)BS * E_DIM;                // [pos][p] f16 (4 MB)

    float dm64 = (float)pow(1.2, -64.0);   // host-side, pure CPU

    hipMemsetAsync(d_out, 0, (size_t)BS * E_DIM * sizeof(float), stream);
    k_pre <<<dim3(1280), dim3(256), 0, stream>>>(x, dw, db, cm, h, wb);
    k_scan<<<dim3(B_N * NCHUNK), dim3(128), 0, stream>>>(h, sb16, fc, hT);
    k_main<<<dim3(1024), dim3(256), 0, stream>>>(hT, sb16, fc, wb, outp, dm64);
    k_ln  <<<dim3(BS / 8), dim3(256), 0, stream>>>(outp, h, gamma, beta);
}